// Round 2
// baseline (734.180 us; speedup 1.0000x reference)
//
#include <hip/hip_runtime.h>
#include <math.h>

#define DIM   2048
#define NREF  30
#define KPAD  32
#define BATCH 16384

// Workspace float offsets
#define WS_VN   0         // 30*2048
#define WS_G    61440     // 900 (+pad)
#define WS_T    62464     // 900 (+pad)
#define WS_W2   63488     // 2048*32   W = V*T, layout [d][KPAD], k=30,31 zeroed
#define WS_S0   129024    // 16384*32  partial S (K-half 0)
#define WS_S1   653312    // 16384*32  partial S (K-half 1)
// total ~1.18M floats = 4.7 MB

__device__ __forceinline__ float block_reduce_sum(float s) {
    #pragma unroll
    for (int off = 32; off > 0; off >>= 1) s += __shfl_down(s, off);
    __shared__ float ws4[4];
    int t = threadIdx.x;
    if ((t & 63) == 0) ws4[t >> 6] = s;
    __syncthreads();
    return ws4[0] + ws4[1] + ws4[2] + ws4[3];
}

__global__ void k_normalize(const float* __restrict__ vec, float* __restrict__ vn) {
    int i = blockIdx.x, t = threadIdx.x;
    const float* v = vec + i * DIM;
    float s = 0.f;
    for (int d = t; d < DIM; d += 256) { float xv = v[d]; s += xv * xv; }
    float tot = block_reduce_sum(s);
    float scale = 1.f / (sqrtf(tot) + 1e-8f);
    float* o = vn + i * DIM;
    for (int d = t; d < DIM; d += 256) o[d] = v[d] * scale;
}

__global__ void k_gram(const float* __restrict__ vn, float* __restrict__ G) {
    int j = blockIdx.x, i = blockIdx.y, t = threadIdx.x;
    const float* a = vn + i * DIM;
    const float* b = vn + j * DIM;
    float s = 0.f;
    for (int d = t; d < DIM; d += 256) s += a[d] * b[d];
    float tot = block_reduce_sum(s);
    if (t == 0) G[i * NREF + j] = tot;
}

__global__ void k_T(const float* __restrict__ G, float* __restrict__ T) {
    int t = threadIdx.x;  // 64 threads
    __shared__ float Ts[NREF][NREF];
    for (int idx = t; idx < NREF * NREF; idx += 64) Ts[idx / NREF][idx % NREF] = 0.f;
    __syncthreads();
    if (t == 0) Ts[0][0] = 2.f;
    __syncthreads();
    for (int j = 1; j < NREF; j++) {
        float val = 0.f;
        if (t < j) {
            for (int m = t; m < j; m++) val += Ts[t][m] * G[m * NREF + j];
            val *= -2.f;
        }
        if (t < j) Ts[t][j] = val;
        if (t == j) Ts[j][j] = 2.f;
        __syncthreads();
    }
    for (int idx = t; idx < NREF * NREF; idx += 64) T[idx] = Ts[idx / NREF][idx % NREF];
}

// W2[d][k] = sum_{j<=k} vn[j][d]*T[j][k], k=30,31 -> 0
__global__ void k_w2(const float* __restrict__ vn, const float* __restrict__ T,
                     float* __restrict__ W2) {
    int d = blockIdx.x * 256 + threadIdx.x;
    float vr[NREF];
    #pragma unroll
    for (int j = 0; j < NREF; j++) vr[j] = vn[j * DIM + d];
    #pragma unroll
    for (int k = 0; k < KPAD; k++) {
        float acc = 0.f;
        if (k < NREF)
            for (int j = 0; j <= k; j++) acc += vr[j] * T[j * NREF + k];
        W2[(size_t)d * KPAD + k] = acc;
    }
}

// ---- phase 1: S_partial[r][k] = sum_{d in K-half} x[r][d] * W2[d][k] ----
// Quad mapping: lane = rq*4+ql. Wave covers 16 rows; ql = 4-col phase.
// x loads: 16 rows x 64B contiguous per wave-inst (coalescing-equivalent).
// W2 float4 loads (4 distinct addrs/inst, L1/L2-hot). acc[32] per thread.
__global__ __launch_bounds__(256) void k_phase1(const float* __restrict__ x,
                                                const float* __restrict__ W2,
                                                float* __restrict__ Sbase) {
    int tid = threadIdx.x;
    int wave = tid >> 6, lane = tid & 63;
    int rq = lane >> 2, ql = lane & 3;
    int row = blockIdx.x * 64 + wave * 16 + rq;
    int ybase = blockIdx.y * (DIM / 2);
    float* Sout = Sbase + (size_t)blockIdx.y * (BATCH * KPAD);
    const float* xrow = x + (size_t)row * DIM + ybase + ql * 4;

    float acc[KPAD];
    #pragma unroll
    for (int k = 0; k < KPAD; k++) acc[k] = 0.f;

    for (int m = 0; m < 64; m++) {
        float4 x4 = *(const float4*)(xrow + m * 16);
        const float4* w = (const float4*)(W2 + (size_t)(ybase + m * 16 + ql * 4) * KPAD);
        #pragma unroll
        for (int k4 = 0; k4 < 8; k4++) {
            float4 wa = w[k4];        // d+0
            float4 wb = w[8 + k4];    // d+1
            float4 wc = w[16 + k4];   // d+2
            float4 wd = w[24 + k4];   // d+3
            acc[4*k4+0] += x4.x*wa.x + x4.y*wb.x + x4.z*wc.x + x4.w*wd.x;
            acc[4*k4+1] += x4.x*wa.y + x4.y*wb.y + x4.z*wc.y + x4.w*wd.y;
            acc[4*k4+2] += x4.x*wa.z + x4.y*wb.z + x4.z*wc.z + x4.w*wd.z;
            acc[4*k4+3] += x4.x*wa.w + x4.y*wb.w + x4.z*wc.w + x4.w*wd.w;
        }
    }
    // reduce over the 4 col-phase lanes of each quad
    #pragma unroll
    for (int k = 0; k < KPAD; k++) {
        acc[k] += __shfl_xor(acc[k], 1);
        acc[k] += __shfl_xor(acc[k], 2);
    }
    if (ql == 0) {
        float4* sp = (float4*)(Sout + (size_t)row * KPAD);
        #pragma unroll
        for (int k4 = 0; k4 < 8; k4++)
            sp[k4] = make_float4(acc[4*k4+0], acc[4*k4+1], acc[4*k4+2], acc[4*k4+3]);
    }
}

// ---- phase 2: y[r][d] = x[r][d] + bias[d] - sum_k (S0+S1)[r][k] * vn[k][d] ----
// lane = column (2 cols/thread, vt in 60 VGPRs). S staged transposed in LDS:
// ST[k][r] so one broadcast ds_read_b128 serves a 4-row quad.
__global__ __launch_bounds__(256) void k_phase2(const float* __restrict__ x,
                                                const float* __restrict__ S0,
                                                const float* __restrict__ S1,
                                                const float* __restrict__ vn,
                                                const float* __restrict__ bias,
                                                float* __restrict__ y) {
    __shared__ float4 ST4[KPAD * 16];        // ST[k][64 rows] as 16 float4
    float* STf = (float*)ST4;
    int tid = threadIdx.x;
    int d0 = blockIdx.x * 512 + tid;
    int d1 = d0 + 256;
    int rbase = blockIdx.y * 128;

    float vt0[NREF], vt1[NREF];
    #pragma unroll
    for (int k = 0; k < NREF; k++) {
        vt0[k] = vn[k * DIM + d0];
        vt1[k] = vn[k * DIM + d1];
    }
    float b0 = bias[d0], b1 = bias[d1];

    for (int c2 = 0; c2 < 2; c2++) {
        int r0 = rbase + c2 * 64;
        __syncthreads();
        {   // stage ST[k][r] = S0[r0+r][k] + S1[r0+r][k], 2048 floats
            int e = tid * 8, rr = e >> 5, kk = e & 31;   // kk in {0,8,16,24}
            const float* s0p = S0 + (size_t)(r0 + rr) * KPAD + kk;
            const float* s1p = S1 + (size_t)(r0 + rr) * KPAD + kk;
            float4 a0 = *(const float4*)s0p,       a1 = *(const float4*)(s0p + 4);
            float4 c0 = *(const float4*)s1p,       c1 = *(const float4*)(s1p + 4);
            STf[(kk + 0) * 64 + rr] = a0.x + c0.x;
            STf[(kk + 1) * 64 + rr] = a0.y + c0.y;
            STf[(kk + 2) * 64 + rr] = a0.z + c0.z;
            STf[(kk + 3) * 64 + rr] = a0.w + c0.w;
            STf[(kk + 4) * 64 + rr] = a1.x + c1.x;
            STf[(kk + 5) * 64 + rr] = a1.y + c1.y;
            STf[(kk + 6) * 64 + rr] = a1.z + c1.z;
            STf[(kk + 7) * 64 + rr] = a1.w + c1.w;
        }
        __syncthreads();

        for (int rq = 0; rq < 16; rq++) {
            const float* xp = x + (size_t)(r0 + rq * 4) * DIM;
            float y00 = xp[0 * DIM + d0] + b0;
            float y01 = xp[1 * DIM + d0] + b0;
            float y02 = xp[2 * DIM + d0] + b0;
            float y03 = xp[3 * DIM + d0] + b0;
            float y10 = xp[0 * DIM + d1] + b1;
            float y11 = xp[1 * DIM + d1] + b1;
            float y12 = xp[2 * DIM + d1] + b1;
            float y13 = xp[3 * DIM + d1] + b1;
            #pragma unroll
            for (int k = 0; k < NREF; k++) {
                float4 s4 = ST4[k * 16 + rq];     // broadcast b128: s for 4 rows
                y00 -= s4.x * vt0[k];  y01 -= s4.y * vt0[k];
                y02 -= s4.z * vt0[k];  y03 -= s4.w * vt0[k];
                y10 -= s4.x * vt1[k];  y11 -= s4.y * vt1[k];
                y12 -= s4.z * vt1[k];  y13 -= s4.w * vt1[k];
            }
            float* yp = y + (size_t)(r0 + rq * 4) * DIM;
            yp[0 * DIM + d0] = y00;  yp[1 * DIM + d0] = y01;
            yp[2 * DIM + d0] = y02;  yp[3 * DIM + d0] = y03;
            yp[0 * DIM + d1] = y10;  yp[1 * DIM + d1] = y11;
            yp[2 * DIM + d1] = y12;  yp[3 * DIM + d1] = y13;
        }
    }
}

extern "C" void kernel_launch(void* const* d_in, const int* in_sizes, int n_in,
                              void* d_out, int out_size, void* d_ws, size_t ws_size,
                              hipStream_t stream) {
    const float* x    = (const float*)d_in[0];
    const float* vec  = (const float*)d_in[1];
    const float* bias = (const float*)d_in[2];
    float* out = (float*)d_out;
    float* ws  = (float*)d_ws;

    float* vn = ws + WS_VN;
    float* G  = ws + WS_G;
    float* T  = ws + WS_T;
    float* W2 = ws + WS_W2;
    float* S0 = ws + WS_S0;

    k_normalize<<<NREF, 256, 0, stream>>>(vec, vn);
    k_gram<<<dim3(NREF, NREF), 256, 0, stream>>>(vn, G);
    k_T<<<1, 64, 0, stream>>>(G, T);
    k_w2<<<DIM / 256, 256, 0, stream>>>(vn, T, W2);
    k_phase1<<<dim3(BATCH / 64, 2), 256, 0, stream>>>(x, W2, S0);
    k_phase2<<<dim3(4, BATCH / 128), 256, 0, stream>>>(x, S0, ws + WS_S1, vn, bias, out);
}

// Round 3
// 320.047 us; speedup vs baseline: 2.2940x; 2.2940x over previous
//
#include <hip/hip_runtime.h>
#include <math.h>

#define DIM   2048
#define NREF  30
#define KPAD  32
#define BATCH 16384

typedef __attribute__((ext_vector_type(8))) short short8;
typedef __attribute__((ext_vector_type(4))) float f32x4;

// Workspace float offsets
#define WS_VN   0         // 30*2048 fp32
#define WS_G    61440     // 1024
#define WS_T    62464     // 1024
#define WS_W2   63488     // 2048*32 fp32, k=30,31 zeroed
#define WS_FP1  129024    // bf16 B-frags of W2: [64 kstep][2 ntile][64 lane][8]  (128 KB)
#define WS_FP2  161792    // bf16 B-frags of V^T: [128 ctile][64 lane][8]         (128 KB)
#define WS_S    194560    // bf16 S [16384][32]                                   (1 MB)
// total 456704 floats ~1.83 MB

__device__ __forceinline__ unsigned short f2bf(float f) {
    unsigned u = __float_as_uint(f);
    u += 0x7FFF + ((u >> 16) & 1);          // round-to-nearest-even
    return (unsigned short)(u >> 16);
}

__device__ __forceinline__ float block_reduce_sum(float s) {
    #pragma unroll
    for (int off = 32; off > 0; off >>= 1) s += __shfl_down(s, off);
    __shared__ float ws4[4];
    int t = threadIdx.x;
    if ((t & 63) == 0) ws4[t >> 6] = s;
    __syncthreads();
    return ws4[0] + ws4[1] + ws4[2] + ws4[3];
}

__global__ void k_normalize(const float* __restrict__ vec, float* __restrict__ vn) {
    int i = blockIdx.x, t = threadIdx.x;
    const float* v = vec + i * DIM;
    float s = 0.f;
    for (int d = t; d < DIM; d += 256) { float xv = v[d]; s += xv * xv; }
    float tot = block_reduce_sum(s);
    float scale = 1.f / (sqrtf(tot) + 1e-8f);
    float* o = vn + i * DIM;
    for (int d = t; d < DIM; d += 256) o[d] = v[d] * scale;
}

__global__ void k_gram(const float* __restrict__ vn, float* __restrict__ G) {
    int j = blockIdx.x, i = blockIdx.y, t = threadIdx.x;
    const float* a = vn + i * DIM;
    const float* b = vn + j * DIM;
    float s = 0.f;
    for (int d = t; d < DIM; d += 256) s += a[d] * b[d];
    float tot = block_reduce_sum(s);
    if (t == 0) G[i * NREF + j] = tot;
}

__global__ void k_T(const float* __restrict__ G, float* __restrict__ T) {
    int t = threadIdx.x;  // 64 threads
    __shared__ float Ts[NREF][NREF];
    for (int idx = t; idx < NREF * NREF; idx += 64) Ts[idx / NREF][idx % NREF] = 0.f;
    __syncthreads();
    if (t == 0) Ts[0][0] = 2.f;
    __syncthreads();
    for (int j = 1; j < NREF; j++) {
        float val = 0.f;
        if (t < j) {
            for (int m = t; m < j; m++) val += Ts[t][m] * G[m * NREF + j];
            val *= -2.f;
        }
        if (t < j) Ts[t][j] = val;
        if (t == j) Ts[j][j] = 2.f;
        __syncthreads();
    }
    for (int idx = t; idx < NREF * NREF; idx += 64) T[idx] = Ts[idx / NREF][idx % NREF];
}

// W2[d][k] = sum_{j<=k} vn[j][d]*T[j][k]  (fp32, k=30,31 -> 0)
__global__ void k_w2(const float* __restrict__ vn, const float* __restrict__ T,
                     float* __restrict__ W2) {
    int d = blockIdx.x * 256 + threadIdx.x;
    float vr[NREF];
    #pragma unroll
    for (int j = 0; j < NREF; j++) vr[j] = vn[j * DIM + d];
    #pragma unroll
    for (int k = 0; k < KPAD; k++) {
        float acc = 0.f;
        if (k < NREF)
            for (int j = 0; j <= k; j++) acc += vr[j] * T[j * NREF + k];
        W2[(size_t)d * KPAD + k] = acc;
    }
}

// Pack W2 into MFMA B-fragment order for phase1.
// B[k][n] for tile (kstep, ntile): lane holds k = (lane>>4)*8+j, n = lane&15.
__global__ void k_pack1(const float* __restrict__ W2, unsigned short* __restrict__ fp1) {
    int g = blockIdx.x * 256 + threadIdx.x;   // 0..8191
    int ks = g >> 7, nt = (g >> 6) & 1, lane = g & 63;
    int q = lane >> 4, n = lane & 15;
    unsigned short tmp[8];
    #pragma unroll
    for (int j = 0; j < 8; j++)
        tmp[j] = f2bf(W2[(size_t)(ks * 32 + q * 8 + j) * KPAD + nt * 16 + n]);
    short8* out = (short8*)fp1;
    short8 v;
    #pragma unroll
    for (int j = 0; j < 8; j++) v[j] = (short)tmp[j];
    out[(ks * 2 + nt) * 64 + lane] = v;
}

// Pack V^T into MFMA B-fragment order for phase2.
// B[k][n]: k = reflection idx (pad 30->32 with 0), n = output column.
__global__ void k_pack2(const float* __restrict__ vn, unsigned short* __restrict__ fp2) {
    int g = blockIdx.x * 256 + threadIdx.x;   // 0..8191
    int ct = g >> 6, lane = g & 63;
    int q = lane >> 4, n = lane & 15;
    short8 v;
    #pragma unroll
    for (int j = 0; j < 8; j++) {
        int k = q * 8 + j;
        float f = (k < NREF) ? vn[(size_t)k * DIM + ct * 16 + n] : 0.f;
        v[j] = (short)f2bf(f);
    }
    ((short8*)fp2)[ct * 64 + lane] = v;
}

// ---- phase 1: S = x * W2 (bf16 MFMA, fp32 accum) ----
// Block: 4 waves, 16 rows, waves split K 4-way (512 each = 16 k-steps of 32).
// A-frag: x fp32 loaded 32B/lane coalesced, converted in-register.
// B-frag: one dwordx4 per tile from pre-packed fp1 (L2-resident).
__global__ __launch_bounds__(256) void k_phase1(const float* __restrict__ x,
                                                const short8* __restrict__ fp1,
                                                unsigned short* __restrict__ S) {
    int tid = threadIdx.x;
    int wave = tid >> 6, lane = tid & 63;
    int m = lane & 15, q = lane >> 4;
    int r0 = blockIdx.x * 16;
    int kb = wave * 512;

    const float* xp = x + (size_t)(r0 + m) * DIM + kb + q * 8;

    f32x4 acc0 = {0.f, 0.f, 0.f, 0.f};
    f32x4 acc1 = {0.f, 0.f, 0.f, 0.f};

    #pragma unroll 4
    for (int ks = 0; ks < 16; ks++) {
        const float4* p = (const float4*)(xp + ks * 32);
        float4 xa = p[0];
        float4 xb = p[1];
        short8 a;
        a[0] = (short)f2bf(xa.x); a[1] = (short)f2bf(xa.y);
        a[2] = (short)f2bf(xa.z); a[3] = (short)f2bf(xa.w);
        a[4] = (short)f2bf(xb.x); a[5] = (short)f2bf(xb.y);
        a[6] = (short)f2bf(xb.z); a[7] = (short)f2bf(xb.w);
        int ksg = wave * 16 + ks;
        short8 b0 = fp1[(ksg * 2 + 0) * 64 + lane];
        short8 b1 = fp1[(ksg * 2 + 1) * 64 + lane];
        acc0 = __builtin_amdgcn_mfma_f32_16x16x32_bf16(a, b0, acc0, 0, 0, 0);
        acc1 = __builtin_amdgcn_mfma_f32_16x16x32_bf16(a, b1, acc1, 0, 0, 0);
    }

    // cross-wave K reduction in LDS (fp32), then emit S bf16
    __shared__ f32x4 red[4][64][2];   // 8 KB
    red[wave][lane][0] = acc0;
    red[wave][lane][1] = acc1;
    __syncthreads();
    if (tid < 64) {
        f32x4 s0 = red[0][tid][0], s1 = red[0][tid][1];
        #pragma unroll
        for (int w = 1; w < 4; w++) { s0 += red[w][tid][0]; s1 += red[w][tid][1]; }
        int mq = tid & 15, qq = tid >> 4;
        #pragma unroll
        for (int reg = 0; reg < 4; reg++) {
            size_t row = r0 + qq * 4 + reg;
            S[row * KPAD + mq]      = f2bf(s0[reg]);
            S[row * KPAD + 16 + mq] = f2bf(s1[reg]);
        }
    }
}

// ---- phase 2: y = x + bias - S * V^T (bf16 MFMA K=32, fp32 identity) ----
// Block: 4 waves, 16 rows x 2048 cols; wave w covers cols [w*512, w*512+512).
// A-frag (S row-strip) hoisted: one 16B load. Per 16-col tile: 1 B-frag load,
// 1 MFMA, epilogue of 4 dense-line x loads + 4 stores.
__global__ __launch_bounds__(256) void k_phase2(const float* __restrict__ x,
                                                const unsigned short* __restrict__ S,
                                                const short8* __restrict__ fp2,
                                                const float* __restrict__ bias,
                                                float* __restrict__ y) {
    int tid = threadIdx.x;
    int wave = tid >> 6, lane = tid & 63;
    int m = lane & 15, q = lane >> 4;
    int r0 = blockIdx.x * 16;
    int c0 = wave * 512;

    short8 a = *(const short8*)(S + (size_t)(r0 + m) * KPAD + q * 8);
    f32x4 zero = {0.f, 0.f, 0.f, 0.f};
    int rbase = r0 + q * 4;

    #pragma unroll 2
    for (int t = 0; t < 32; t++) {
        int col = c0 + t * 16;
        short8 b = fp2[(wave * 32 + t) * 64 + lane];
        f32x4 p = __builtin_amdgcn_mfma_f32_16x16x32_bf16(a, b, zero, 0, 0, 0);
        int cc = col + m;
        float bi = bias[cc];
        const float* xc = x + (size_t)rbase * DIM + cc;
        float* yc = y + (size_t)rbase * DIM + cc;
        yc[0 * DIM] = xc[0 * DIM] + bi - p[0];
        yc[1 * DIM] = xc[1 * DIM] + bi - p[1];
        yc[2 * DIM] = xc[2 * DIM] + bi - p[2];
        yc[3 * DIM] = xc[3 * DIM] + bi - p[3];
    }
}

extern "C" void kernel_launch(void* const* d_in, const int* in_sizes, int n_in,
                              void* d_out, int out_size, void* d_ws, size_t ws_size,
                              hipStream_t stream) {
    const float* x    = (const float*)d_in[0];
    const float* vec  = (const float*)d_in[1];
    const float* bias = (const float*)d_in[2];
    float* out = (float*)d_out;
    float* ws  = (float*)d_ws;

    float* vn = ws + WS_VN;
    float* G  = ws + WS_G;
    float* T  = ws + WS_T;
    float* W2 = ws + WS_W2;
    unsigned short* fp1 = (unsigned short*)(ws + WS_FP1);
    unsigned short* fp2 = (unsigned short*)(ws + WS_FP2);
    unsigned short* S   = (unsigned short*)(ws + WS_S);

    k_normalize<<<NREF, 256, 0, stream>>>(vec, vn);
    k_gram<<<dim3(NREF, NREF), 256, 0, stream>>>(vn, G);
    k_T<<<1, 64, 0, stream>>>(G, T);
    k_w2<<<DIM / 256, 256, 0, stream>>>(vn, T, W2);
    k_pack1<<<32, 256, 0, stream>>>(W2, fp1);
    k_pack2<<<32, 256, 0, stream>>>(vn, fp2);
    k_phase1<<<BATCH / 16, 256, 0, stream>>>(x, (const short8*)fp1, S);
    k_phase2<<<BATCH / 16, 256, 0, stream>>>(x, S, (const short8*)fp2, bias, out);
}